// Round 7
// baseline (7902.854 us; speedup 1.0000x reference)
//
#include <hip/hip_runtime.h>
#include <stdint.h>

// ---------------------------------------------------------------------------
// Model constants
// ---------------------------------------------------------------------------
#define BATCH       64
#define SEQ_LEN     2048
#define D_MODEL     128
#define WIN         64
#define NWIN        64
#define PRED_LEN    4
#define XSTRIDE     2052   // SEQ_LEN + PRED_LEN
#define NTHREADS    512    // 8 waves: wave w owns j in [16w, 16w+16)
#define MAINB       4      // 4 blocks x 16 batch
#define WINB        256    // 256 blocks x 16 windows
#define XCHUNK      768    // x staging chunk (48 KB LDS)
#define HSTRIDE     136    // h row stride in halves (272B = 68 dwords, s=17 -> even bank spread)

typedef _Float16 half8 __attribute__((ext_vector_type(8)));
typedef float    v4f   __attribute__((ext_vector_type(4)));

#define PIN(x)  asm volatile("" : "+v"(x))

__device__ __forceinline__ const float* launder(const float* p) {
    uintptr_t v = (uintptr_t)p; asm volatile("" : "+s"(v)); return (const float*)v;
}
__device__ __forceinline__ const _Float16* launder16(const _Float16* p) {
    uintptr_t v = (uintptr_t)p; asm volatile("" : "+s"(v)); return (const _Float16*)v;
}

// ---------------------------------------------------------------------------
// Threefry-2x32 (exact jax implementation)
// ---------------------------------------------------------------------------
__device__ __forceinline__ uint32_t rotl32(uint32_t v, int d) {
    return (v << d) | (v >> (32 - d));
}
__device__ __forceinline__ void threefry2x32(uint32_t k0, uint32_t k1,
                                             uint32_t x0, uint32_t x1,
                                             uint32_t& o0, uint32_t& o1) {
    uint32_t ks0 = k0, ks1 = k1, ks2 = k0 ^ k1 ^ 0x1BD11BDAu;
    x0 += ks0; x1 += ks1;
#define TF_R(r) { x0 += x1; x1 = rotl32(x1, r); x1 ^= x0; }
    TF_R(13) TF_R(15) TF_R(26) TF_R(6)
    x0 += ks1; x1 += ks2 + 1u;
    TF_R(17) TF_R(29) TF_R(16) TF_R(24)
    x0 += ks2; x1 += ks0 + 2u;
    TF_R(13) TF_R(15) TF_R(26) TF_R(6)
    x0 += ks0; x1 += ks1 + 3u;
    TF_R(17) TF_R(29) TF_R(16) TF_R(24)
    x0 += ks1; x1 += ks2 + 4u;
    TF_R(13) TF_R(15) TF_R(26) TF_R(6)
    x0 += ks2; x1 += ks0 + 5u;
#undef TF_R
    o0 = x0; o1 = x1;
}

__device__ __forceinline__ float sigf(float x) { return 1.f / (1.f + __expf(-x)); }
__device__ __forceinline__ float tanhf_(float x) {
    float e = __expf(2.f * x);
    return 1.f - 2.f / (e + 1.f);
}

// ---------------------------------------------------------------------------
// init: copy batch_x into strided x_ext
// ---------------------------------------------------------------------------
__global__ void init_kernel(const float* __restrict__ bx, float* __restrict__ xext) {
    int idx = blockIdx.x * 256 + threadIdx.x;
    if (idx < BATCH * SEQ_LEN) {
        int b = idx >> 11, t = idx & 2047;
        xext[(size_t)b * XSTRIDE + t] = bx[idx];
    }
}

// ---------------------------------------------------------------------------
// convert: Wh (fp32) -> f16 workspace copies (once per launch)
// ---------------------------------------------------------------------------
__global__ void convert_kernel(const float* __restrict__ Wg, const float* __restrict__ Ww,
                               _Float16* __restrict__ g16, _Float16* __restrict__ w16) {
    int idx = blockIdx.x * 256 + threadIdx.x;
    if (idx < 384 * 128) {
        g16[idx] = (_Float16)Wg[idx];
        w16[idx] = (_Float16)Ww[idx];
    }
}

// ---------------------------------------------------------------------------
// prep: per-batch mean/std (fp64, ddof=1), threefry starts, Q gather
// ---------------------------------------------------------------------------
__global__ void prep_kernel(const float* __restrict__ xext,
                            int* __restrict__ starts, float* __restrict__ Q,
                            int T, int stepIdx) {
    int b = blockIdx.x, tid = threadIdx.x;
    const float* xb = xext + (size_t)b * XSTRIDE;

    double s = 0.0, s2 = 0.0;
    for (int t = tid; t < T; t += 256) { double v = (double)xb[t]; s += v; s2 += v * v; }
    __shared__ double rs[256], rs2[256];
    rs[tid] = s; rs2[tid] = s2;
    __syncthreads();
    for (int off = 128; off > 0; off >>= 1) {
        if (tid < off) { rs[tid] += rs[tid + off]; rs2[tid] += rs2[tid + off]; }
        __syncthreads();
    }
    __shared__ float thr_s;
    if (tid == 0) {
        double mean = rs[0] / (double)T;
        double var = (rs2[0] - (double)T * mean * mean) / (double)(T - 1);
        if (var < 0.0) var = 0.0;
        thr_s = (float)(mean + 1.48 * sqrt(var));
    }
    __syncthreads();

    if (tid < NWIN) {
        uint32_t ka, kb;
        threefry2x32(0u, 42u, 0u, (uint32_t)stepIdx, ka, kb);
        uint32_t A0, B0, A1, B1;
        threefry2x32(ka, kb, 0u, 2u, A0, B0);
        threefry2x32(ka, kb, 1u, 3u, A1, B1);

        uint32_t idx = (uint32_t)(b * NWIN + tid);
        uint32_t q = idx & 2047u;
        uint32_t h0, h1, l0, l1;
        threefry2x32(A0, A1, q, q + 2048u, h0, h1);
        threefry2x32(B0, B1, q, q + 2048u, l0, l1);
        uint32_t hi = (idx < 2048u) ? h0 : h1;
        uint32_t lo = (idx < 2048u) ? l0 : l1;

        uint32_t span = (uint32_t)(T - WIN);
        uint32_t mult = 65536u % span;
        mult = (mult * mult) % span;
        uint32_t off = ((hi % span) * mult + (lo % span)) % span;
        starts[idx] = (int)off;
        Q[idx] = (xb[off + WIN] > thr_s) ? 1.f : 0.f;
    }
}

// ---------------------------------------------------------------------------
// FUSED MFMA GRU.  Block = 16 batch elements (main, blocks 0..3) or 16
// windows (blocks 4..259).  8 waves; wave w owns j in [16w,16w+16).
// Per step: D[batch=16][gate-rows 48 per wave] = A(h,f16) x B(Wh,f16) via
// 12x mfma_f32_16x16x32_f16, then per-lane epilogue on 4 (batch,j) cells
// (C layout: col=lane&15 -> j, row=quad*4+reg -> batch).  B-fragments
// (48 VGPRs) loaded once from laundered global f16 weights; h ping-pongs
// through LDS as f16 (A layout: row=lane&15, k=quad*8+i); h carried fp32
// in registers for the recurrence.  LDS ~58KB caps occupancy at 2 blocks/CU
// = 4 waves/EU, matching __launch_bounds__(512,4)'s 128-VGPR budget, so the
// allocator has no occupancy incentive to spill (demand ~110).
// ---------------------------------------------------------------------------
#define STEP(CUR, XS)                                                           \
    do {                                                                        \
        v4f cr = {br, br, br, br};                                              \
        v4f cz = {bz, bz, bz, bz};                                              \
        v4f cn = {bhn, bhn, bhn, bhn};                                          \
        const _Float16* hb = &hsh[CUR][0];                                      \
        half8 A0 = *(const half8*)(hb + aoff);                                  \
        half8 A1 = *(const half8*)(hb + aoff + 32);                             \
        half8 A2 = *(const half8*)(hb + aoff + 64);                             \
        half8 A3 = *(const half8*)(hb + aoff + 96);                             \
        cr = __builtin_amdgcn_mfma_f32_16x16x32_f16(A0, Bf[0][0], cr, 0, 0, 0); \
        cz = __builtin_amdgcn_mfma_f32_16x16x32_f16(A0, Bf[1][0], cz, 0, 0, 0); \
        cn = __builtin_amdgcn_mfma_f32_16x16x32_f16(A0, Bf[2][0], cn, 0, 0, 0); \
        cr = __builtin_amdgcn_mfma_f32_16x16x32_f16(A1, Bf[0][1], cr, 0, 0, 0); \
        cz = __builtin_amdgcn_mfma_f32_16x16x32_f16(A1, Bf[1][1], cz, 0, 0, 0); \
        cn = __builtin_amdgcn_mfma_f32_16x16x32_f16(A1, Bf[2][1], cn, 0, 0, 0); \
        cr = __builtin_amdgcn_mfma_f32_16x16x32_f16(A2, Bf[0][2], cr, 0, 0, 0); \
        cz = __builtin_amdgcn_mfma_f32_16x16x32_f16(A2, Bf[1][2], cz, 0, 0, 0); \
        cn = __builtin_amdgcn_mfma_f32_16x16x32_f16(A2, Bf[2][2], cn, 0, 0, 0); \
        cr = __builtin_amdgcn_mfma_f32_16x16x32_f16(A3, Bf[0][3], cr, 0, 0, 0); \
        cz = __builtin_amdgcn_mfma_f32_16x16x32_f16(A3, Bf[1][3], cz, 0, 0, 0); \
        cn = __builtin_amdgcn_mfma_f32_16x16x32_f16(A3, Bf[2][3], cn, 0, 0, 0); \
        float4 xv = *(const float4*)&xT[(XS) * 16 + quad * 4];                  \
        float xa0 = xv.x, xa1 = xv.y, xa2 = xv.z, xa3 = xv.w;                   \
        float xa[4] = {xa0, xa1, xa2, xa3};                                     \
        _Pragma("unroll")                                                       \
        for (int r_ = 0; r_ < 4; ++r_) {                                        \
            float rr = sigf(fmaf(xa[r_], wir, cr[r_]));                         \
            float zz = sigf(fmaf(xa[r_], wiz, cz[r_]));                         \
            float nv = tanhf_(fmaf(xa[r_], win, bin) + rr * cn[r_]);            \
            hold[r_] = fmaf(zz, hold[r_] - nv, nv);                             \
            hsh[(CUR) ^ 1][woff + r_ * HSTRIDE] = (_Float16)hold[r_];           \
        }                                                                       \
        __syncthreads();                                                        \
    } while (0)

__global__ __launch_bounds__(NTHREADS, 4)
void gru_fused_kernel(const float* __restrict__ xext, float* __restrict__ hstate,
                      const int* __restrict__ starts, float* __restrict__ S,
                      const _Float16* wh16g, const float* Wi_g_,
                      const float* bi_g_, const float* bh_g_,
                      const _Float16* wh16w, const float* Wi_w_,
                      const float* bi_w_, const float* bh_w_,
                      int L, int initFlag) {
    __shared__ __align__(16) _Float16 hsh[2][16 * HSTRIDE];  // ping-pong h (f16)
    __shared__ __align__(16) float xT[XCHUNK * 16];          // x chunk [t][cell-row]

    const int tid  = threadIdx.x;
    const int wv   = tid >> 6;        // wave index -> j slice
    const int lane = tid & 63;
    const int quad = lane >> 4;
    const int ncol = lane & 15;       // C col / A row / B col
    const int j    = wv * 16 + ncol;  // this lane's hidden unit (epilogue & B)
    const bool isMain = (blockIdx.x < MAINB);

    const _Float16* wh16 = launder16(isMain ? wh16g : wh16w);
    const float* Wi = launder(isMain ? Wi_g_ : Wi_w_);
    const float* bi = launder(isMain ? bi_g_ : bi_w_);
    const float* bh = launder(isMain ? bh_g_ : bh_w_);

    // ---- B-fragments: lane holds Wh[g*128 + j][k = 32*kt + 8*quad + i] ----
    half8 Bf[3][4];
#pragma unroll
    for (int g = 0; g < 3; ++g)
#pragma unroll
        for (int kt = 0; kt < 4; ++kt)
            Bf[g][kt] = *(const half8*)(wh16 + (size_t)(g * 128 + j) * 128 + kt * 32 + quad * 8);
#pragma unroll
    for (int g = 0; g < 3; ++g)
#pragma unroll
        for (int kt = 0; kt < 4; ++kt) PIN(Bf[g][kt]);

    float wir = Wi[j], wiz = Wi[j + 128], win = Wi[j + 256];
    float br  = bi[j] + bh[j];
    float bz  = bi[j + 128] + bh[j + 128];
    float bin = bi[j + 256], bhn = bh[j + 256];
    PIN(wir); PIN(wiz); PIN(win); PIN(br); PIN(bz); PIN(bin); PIN(bhn);

    const int aoff = ncol * HSTRIDE + quad * 8;        // A-frag base (halves)
    const int woff = (quad * 4) * HSTRIDE + j;         // h-write base (halves)

    float hold[4];

    if (isMain) {
        const int b16 = blockIdx.x * 16;
#pragma unroll
        for (int r_ = 0; r_ < 4; ++r_) {
            hold[r_] = initFlag ? 0.f
                                : hstate[(size_t)(b16 + quad * 4 + r_) * D_MODEL + j];
            hsh[0][woff + r_ * HSTRIDE] = (_Float16)hold[r_];
        }
        int t = 0;
        while (t < L) {
            int lim = L - t; if (lim > XCHUNK) lim = XCHUNK;
            __syncthreads();   // prior chunk's reads done / h-staging visible
            for (int idx = tid; idx < (lim << 4); idx += NTHREADS) {
                int tc = idx >> 4, bb = idx & 15;
                xT[idx] = xext[(size_t)(b16 + bb) * XSTRIDE + (t + tc)];
            }
            __syncthreads();
            int s = 0;
            for (; s + 1 < lim; s += 2) { STEP(0, s); STEP(1, s + 1); }
            if (s < lim) STEP(0, s);
            t += lim;
        }
#pragma unroll
        for (int r_ = 0; r_ < 4; ++r_)
            hstate[(size_t)(b16 + quad * 4 + r_) * D_MODEL + j] = hold[r_];
    } else {
        const int wb = blockIdx.x - MAINB;   // 0..255, 16 windows each
        for (int idx = tid; idx < WIN * 16; idx += NTHREADS) {
            int ww = idx & 15, tt = idx >> 4;
            int widx = (wb << 4) + ww;
            xT[idx] = xext[(size_t)(widx >> 6) * XSTRIDE + starts[widx] + tt];
        }
#pragma unroll
        for (int r_ = 0; r_ < 4; ++r_) {
            hold[r_] = 0.f;
            hsh[0][woff + r_ * HSTRIDE] = (_Float16)0.f;
        }
        __syncthreads();
        for (int s = 0; s < WIN; s += 2) { STEP(0, s); STEP(1, s + 1); }
#pragma unroll
        for (int r_ = 0; r_ < 4; ++r_)
            S[(size_t)((wb << 4) + quad * 4 + r_) * D_MODEL + j] = hold[r_];
    }
}

// ---------------------------------------------------------------------------
// finalize: attention + output.  One wave per batch element.
// ---------------------------------------------------------------------------
__global__ void finalize_kernel(float* __restrict__ xext,
                                const float* __restrict__ hstate,
                                const float* __restrict__ S,
                                const float* __restrict__ Q,
                                const float* __restrict__ Wd, const float* __restrict__ bd,
                                const float* __restrict__ Wc, const float* __restrict__ bc,
                                float* __restrict__ out, int stepIdx) {
    int b = blockIdx.x;
    int m = threadIdx.x;  // 64 threads = 1 wave

    __shared__ float Hs[D_MODEL];
    Hs[m]      = hstate[b * D_MODEL + m];
    Hs[m + 64] = hstate[b * D_MODEL + 64 + m];
    __syncthreads();

    const float* Srow = S + (size_t)(b * NWIN + m) * D_MODEL;
    float acc = 0.f;
#pragma unroll
    for (int jj = 0; jj < D_MODEL; ++jj)
        acc = fmaf(Hs[jj], Srow[jj], acc);

    float mx = acc;
#pragma unroll
    for (int d = 1; d < 64; d <<= 1) mx = fmaxf(mx, __shfl_xor(mx, d));
    float e = __expf(acc - mx);
    float se = e;
#pragma unroll
    for (int d = 1; d < 64; d <<= 1) se += __shfl_xor(se, d);
    float A = e / se;

    float qa = Q[b * NWIN + m] * A;
#pragma unroll
    for (int d = 1; d < 64; d <<= 1) qa += __shfl_xor(qa, d);

    float po = Hs[m] * Wd[m] + Hs[m + 64] * Wd[m + 64];
#pragma unroll
    for (int d = 1; d < 64; d <<= 1) po += __shfl_xor(po, d);

    if (m == 0) {
        float o = po + bd[0];
        float u = sigf(fmaf(qa, Wc[0], bc[0]));
        float y = o + u;
        xext[(size_t)b * XSTRIDE + SEQ_LEN + stepIdx] = y;
        out[b * PRED_LEN + stepIdx] = y;
        out[BATCH * PRED_LEN + b * PRED_LEN + stepIdx] = u;
    }
}

// ---------------------------------------------------------------------------
// kernel_launch
// ---------------------------------------------------------------------------
extern "C" void kernel_launch(void* const* d_in, const int* in_sizes, int n_in,
                              void* d_out, int out_size, void* d_ws, size_t ws_size,
                              hipStream_t stream) {
    const float* batch_x = (const float*)d_in[0];
    const float* Wi_g = (const float*)d_in[4];
    const float* Wh_g = (const float*)d_in[5];
    const float* bi_g = (const float*)d_in[6];
    const float* bh_g = (const float*)d_in[7];
    const float* Wi_w = (const float*)d_in[8];
    const float* Wh_w = (const float*)d_in[9];
    const float* bi_w = (const float*)d_in[10];
    const float* bh_w = (const float*)d_in[11];
    const float* Wd   = (const float*)d_in[12];
    const float* bd   = (const float*)d_in[13];
    const float* Wc   = (const float*)d_in[16];
    const float* bc   = (const float*)d_in[17];
    float* out = (float*)d_out;

    // workspace layout
    float* ws = (float*)d_ws;
    float* xext   = ws;                                   // 131328 f
    float* hstate = xext + BATCH * XSTRIDE;               // 8192 f
    float* Q      = hstate + BATCH * D_MODEL;             // 4096 f
    float* Sbuf   = Q + BATCH * NWIN;                     // 524288 f
    int*   starts = (int*)(Sbuf + (size_t)BATCH * NWIN * D_MODEL); // 4096 i
    _Float16* wh16g = (_Float16*)(starts + BATCH * NWIN); // 49152 h
    _Float16* wh16w = wh16g + 384 * 128;                  // 49152 h

    init_kernel<<<512, 256, 0, stream>>>(batch_x, xext);
    convert_kernel<<<192, 256, 0, stream>>>(Wh_g, Wh_w, wh16g, wh16w);

    for (int i = 0; i < PRED_LEN; ++i) {
        int T = SEQ_LEN + i;
        int L = (i == 0) ? SEQ_LEN : (SEQ_LEN - 1 + i);

        prep_kernel<<<BATCH, 256, 0, stream>>>(xext, starts, Q, T, i);
        gru_fused_kernel<<<MAINB + WINB, NTHREADS, 0, stream>>>(
            xext, hstate, starts, Sbuf,
            wh16g, Wi_g, bi_g, bh_g,
            wh16w, Wi_w, bi_w, bh_w,
            L, (i == 0) ? 1 : 0);
        finalize_kernel<<<BATCH, 64, 0, stream>>>(xext, hstate, Sbuf, Q,
                                                  Wd, bd, Wc, bc, out, i);
    }
}

// Round 8
// 3877.138 us; speedup vs baseline: 2.0383x; 2.0383x over previous
//
#include <hip/hip_runtime.h>
#include <stdint.h>

// ---------------------------------------------------------------------------
// Model constants
// ---------------------------------------------------------------------------
#define BATCH       64
#define SEQ_LEN     2048
#define D_MODEL     128
#define WIN         64
#define NWIN        64
#define PRED_LEN    4
#define XSTRIDE     2052   // SEQ_LEN + PRED_LEN
#define NTH         256    // 4 waves; thread = (j, kh): j hidden unit, kh k-half
#define MAINB       64     // one block per batch element
#define WINB        256    // 256 blocks x 16 windows = 4096
#define WPB         16

// xsh sized so block LDS ~55 KB: floor(160K / 55K) = 2 blocks/CU
// -> 8 waves/CU = 2 waves/EU -> register budget 256 VGPRs.  This is the
// LDS-limited-occupancy mechanism (same one that gives m97-style GEMMs
// 164 VGPRs).  The array is genuinely used (x staging) so it cannot be DCE'd
// (round-6 lesson: fully-dead pad arrays are eliminated).
#define XSH_FLOATS  13696

typedef _Float16 h2 __attribute__((ext_vector_type(2)));

#define PIN(x)  asm volatile("" : "+v"(x))

__device__ __forceinline__ const float* launder(const float* p) {
    uintptr_t v = (uintptr_t)p; asm volatile("" : "+s"(v)); return (const float*)v;
}
__device__ __forceinline__ const _Float16* launder16(const _Float16* p) {
    uintptr_t v = (uintptr_t)p; asm volatile("" : "+s"(v)); return (const _Float16*)v;
}

// packed-f16 dot2: acc += a.x*b.x + a.y*b.y  (V_DOT2_F32_F16)
__device__ __forceinline__ float dot2f(float a, float b, float acc) {
#if __has_builtin(__builtin_amdgcn_fdot2)
    return __builtin_amdgcn_fdot2(__builtin_bit_cast(h2, a),
                                  __builtin_bit_cast(h2, b), acc, false);
#else
    h2 av = __builtin_bit_cast(h2, a), bv = __builtin_bit_cast(h2, b);
    return fmaf((float)av.x, (float)bv.x, fmaf((float)av.y, (float)bv.y, acc));
#endif
}

// ---------------------------------------------------------------------------
// Threefry-2x32 (exact jax implementation)
// ---------------------------------------------------------------------------
__device__ __forceinline__ uint32_t rotl32(uint32_t v, int d) {
    return (v << d) | (v >> (32 - d));
}
__device__ __forceinline__ void threefry2x32(uint32_t k0, uint32_t k1,
                                             uint32_t x0, uint32_t x1,
                                             uint32_t& o0, uint32_t& o1) {
    uint32_t ks0 = k0, ks1 = k1, ks2 = k0 ^ k1 ^ 0x1BD11BDAu;
    x0 += ks0; x1 += ks1;
#define TF_R(r) { x0 += x1; x1 = rotl32(x1, r); x1 ^= x0; }
    TF_R(13) TF_R(15) TF_R(26) TF_R(6)
    x0 += ks1; x1 += ks2 + 1u;
    TF_R(17) TF_R(29) TF_R(16) TF_R(24)
    x0 += ks2; x1 += ks0 + 2u;
    TF_R(13) TF_R(15) TF_R(26) TF_R(6)
    x0 += ks0; x1 += ks1 + 3u;
    TF_R(17) TF_R(29) TF_R(16) TF_R(24)
    x0 += ks1; x1 += ks2 + 4u;
    TF_R(13) TF_R(15) TF_R(26) TF_R(6)
    x0 += ks2; x1 += ks0 + 5u;
#undef TF_R
    o0 = x0; o1 = x1;
}

__device__ __forceinline__ float sigf(float x) { return 1.f / (1.f + __expf(-x)); }
__device__ __forceinline__ float tanhf_(float x) {
    float e = __expf(2.f * x);
    return 1.f - 2.f / (e + 1.f);
}

// ---------------------------------------------------------------------------
// init / convert
// ---------------------------------------------------------------------------
__global__ void init_kernel(const float* __restrict__ bx, float* __restrict__ xext) {
    int idx = blockIdx.x * 256 + threadIdx.x;
    if (idx < BATCH * SEQ_LEN) {
        int b = idx >> 11, t = idx & 2047;
        xext[(size_t)b * XSTRIDE + t] = bx[idx];
    }
}

__global__ void convert_kernel(const float* __restrict__ Wg, const float* __restrict__ Ww,
                               _Float16* __restrict__ g16, _Float16* __restrict__ w16) {
    int idx = blockIdx.x * 256 + threadIdx.x;
    if (idx < 384 * 128) {
        g16[idx] = (_Float16)Wg[idx];
        w16[idx] = (_Float16)Ww[idx];
    }
}

// ---------------------------------------------------------------------------
// prep: per-batch mean/std (fp64, ddof=1), threefry starts, Q gather
// ---------------------------------------------------------------------------
__global__ void prep_kernel(const float* __restrict__ xext,
                            int* __restrict__ starts, float* __restrict__ Q,
                            int T, int stepIdx) {
    int b = blockIdx.x, tid = threadIdx.x;
    const float* xb = xext + (size_t)b * XSTRIDE;

    double s = 0.0, s2 = 0.0;
    for (int t = tid; t < T; t += 256) { double v = (double)xb[t]; s += v; s2 += v * v; }
    __shared__ double rs[256], rs2[256];
    rs[tid] = s; rs2[tid] = s2;
    __syncthreads();
    for (int off = 128; off > 0; off >>= 1) {
        if (tid < off) { rs[tid] += rs[tid + off]; rs2[tid] += rs2[tid + off]; }
        __syncthreads();
    }
    __shared__ float thr_s;
    if (tid == 0) {
        double mean = rs[0] / (double)T;
        double var = (rs2[0] - (double)T * mean * mean) / (double)(T - 1);
        if (var < 0.0) var = 0.0;
        thr_s = (float)(mean + 1.48 * sqrt(var));
    }
    __syncthreads();

    if (tid < NWIN) {
        uint32_t ka, kb;
        threefry2x32(0u, 42u, 0u, (uint32_t)stepIdx, ka, kb);
        uint32_t A0, B0, A1, B1;
        threefry2x32(ka, kb, 0u, 2u, A0, B0);
        threefry2x32(ka, kb, 1u, 3u, A1, B1);

        uint32_t idx = (uint32_t)(b * NWIN + tid);
        uint32_t q = idx & 2047u;
        uint32_t h0, h1, l0, l1;
        threefry2x32(A0, A1, q, q + 2048u, h0, h1);
        threefry2x32(B0, B1, q, q + 2048u, l0, l1);
        uint32_t hi = (idx < 2048u) ? h0 : h1;
        uint32_t lo = (idx < 2048u) ? l0 : l1;

        uint32_t span = (uint32_t)(T - WIN);
        uint32_t mult = 65536u % span;
        mult = (mult * mult) % span;
        uint32_t off = ((hi % span) * mult + (lo % span)) % span;
        starts[idx] = (int)off;
        Q[idx] = (xb[off + WIN] > thr_s) ? 1.f : 0.f;
    }
}

// ---------------------------------------------------------------------------
// FUSED GRU (f16-dot2 VALU).  Block = 1 batch element (main, 0..63) or 16
// sequential windows (64..319).  256 threads: tid = j*2 + kh.  Thread holds
// Wh rows (j, j+128, j+256), k-half kh as 96 packed-f16 pairs (96 VGPRs),
// under the 256-VGPR budget enforced by LDS-limited occupancy (2 blocks/CU).
// h ping-pongs through LDS as f16[128]; each ds_read_b128 has 2 distinct
// addresses (kh=0/1) on the same bank quad = free 2-way.  One butterfly
// shuffle (xor 1) completes the 128-dot.  96 dot2 = 192 MACs/thread/step.
// ---------------------------------------------------------------------------
#define GSTEP(CUR, XV)                                                       \
    do {                                                                     \
        float xv_ = (XV);                                                    \
        float ar = 0.f, az = 0.f, an = 0.f;                                  \
        const float4* hp_ = (CUR) ? h1base : h0base;                         \
        _Pragma("unroll")                                                    \
        for (int c = 0; c < 8; ++c) {                                        \
            float4 hv = hp_[c];                                              \
            ar = dot2f(hv.x, wpk[0][4*c+0], ar);                             \
            ar = dot2f(hv.y, wpk[0][4*c+1], ar);                             \
            ar = dot2f(hv.z, wpk[0][4*c+2], ar);                             \
            ar = dot2f(hv.w, wpk[0][4*c+3], ar);                             \
            az = dot2f(hv.x, wpk[1][4*c+0], az);                             \
            az = dot2f(hv.y, wpk[1][4*c+1], az);                             \
            az = dot2f(hv.z, wpk[1][4*c+2], az);                             \
            az = dot2f(hv.w, wpk[1][4*c+3], az);                             \
            an = dot2f(hv.x, wpk[2][4*c+0], an);                             \
            an = dot2f(hv.y, wpk[2][4*c+1], an);                             \
            an = dot2f(hv.z, wpk[2][4*c+2], an);                             \
            an = dot2f(hv.w, wpk[2][4*c+3], an);                             \
        }                                                                    \
        ar += __shfl_xor(ar, 1);                                             \
        az += __shfl_xor(az, 1);                                             \
        an += __shfl_xor(an, 1);                                             \
        float r = sigf(fmaf(xv_, wir, br) + ar);                             \
        float z = sigf(fmaf(xv_, wiz, bz) + az);                             \
        float n = tanhf_(fmaf(xv_, win, bin) + r * (an + bhn));              \
        hold = fmaf(z, hold - n, n);                                         \
        if (kh == 0) hsh[(CUR) ^ 1][j] = (_Float16)hold;                     \
        __syncthreads();                                                     \
    } while (0)

__global__
__attribute__((amdgpu_flat_work_group_size(NTH, NTH), amdgpu_waves_per_eu(2, 2)))
void gru_fused_kernel(const float* __restrict__ xext, float* __restrict__ hstate,
                      const int* __restrict__ starts, float* __restrict__ S,
                      const _Float16* wh16g, const float* Wi_g_,
                      const float* bi_g_, const float* bh_g_,
                      const _Float16* wh16w, const float* Wi_w_,
                      const float* bi_w_, const float* bh_w_,
                      int L, int initFlag) {
    __shared__ float xsh[XSH_FLOATS];                // 54784 B: staging + occupancy clamp
    __shared__ __align__(16) _Float16 hsh[2][D_MODEL];

    const int tid = threadIdx.x;
    const int j  = tid >> 1;
    const int kh = tid & 1;
    const bool isMain = (blockIdx.x < MAINB);

    const _Float16* wh16 = launder16(isMain ? wh16g : wh16w);
    const float* Wi = launder(isMain ? Wi_g_ : Wi_w_);
    const float* bi = launder(isMain ? bi_g_ : bi_w_);
    const float* bh = launder(isMain ? bh_g_ : bh_w_);

    // ---- weights: 3 gates x 32 packed-f16 pairs, register-resident ----
    float wpk[3][32];
#pragma unroll
    for (int g = 0; g < 3; ++g) {
        const float4* wp = (const float4*)(wh16 + (size_t)(g * 128 + j) * 128 + kh * 64);
#pragma unroll
        for (int c = 0; c < 8; ++c) {
            float4 v = wp[c];
            wpk[g][4*c+0] = v.x; wpk[g][4*c+1] = v.y;
            wpk[g][4*c+2] = v.z; wpk[g][4*c+3] = v.w;
        }
    }
#pragma unroll
    for (int g = 0; g < 3; ++g)
#pragma unroll
        for (int p = 0; p < 32; ++p) PIN(wpk[g][p]);

    float wir = Wi[j], wiz = Wi[j + 128], win = Wi[j + 256];
    float br  = bi[j] + bh[j];
    float bz  = bi[j + 128] + bh[j + 128];
    float bin = bi[j + 256], bhn = bh[j + 256];
    PIN(wir); PIN(wiz); PIN(win); PIN(br); PIN(bz); PIN(bin); PIN(bhn);

    const float4* h0base = (const float4*)&hsh[0][kh * 64];
    const float4* h1base = (const float4*)&hsh[1][kh * 64];

    float hold;

    if (isMain) {
        const int b = blockIdx.x;
        for (int t = tid; t < L; t += NTH)
            xsh[t] = xext[(size_t)b * XSTRIDE + t];
        hold = initFlag ? 0.f : hstate[b * D_MODEL + j];
        if (tid < D_MODEL)
            hsh[0][tid] = initFlag ? (_Float16)0.f
                                   : (_Float16)hstate[b * D_MODEL + tid];
        __syncthreads();

        int t = 0;
        for (; t + 1 < L; t += 2) {
            GSTEP(0, xsh[t]);
            GSTEP(1, xsh[t + 1]);
        }
        if (t < L) GSTEP(0, xsh[t]);
        if (kh == 0) hstate[b * D_MODEL + j] = hold;
    } else {
        const int wb = blockIdx.x - MAINB;
        for (int w = 0; w < WPB; ++w) {
            int widx = wb * WPB + w;
            int b = widx >> 6;
            int st = starts[widx];
            if (tid < WIN) xsh[tid] = xext[(size_t)b * XSTRIDE + st + tid];
            if (tid < D_MODEL) hsh[0][tid] = (_Float16)0.f;
            hold = 0.f;
            __syncthreads();

#pragma unroll 1
            for (int s = 0; s < WIN; s += 2) {
                GSTEP(0, xsh[s]);
                GSTEP(1, xsh[s + 1]);
            }
            if (kh == 0) S[(size_t)widx * D_MODEL + j] = hold;
            // GSTEP's trailing barrier orders this window's last LDS ops
            // before the next window's staging; S-store is register-sourced.
            __syncthreads();
        }
    }
}

// ---------------------------------------------------------------------------
// finalize: attention + output.  One wave per batch element.
// ---------------------------------------------------------------------------
__global__ void finalize_kernel(float* __restrict__ xext,
                                const float* __restrict__ hstate,
                                const float* __restrict__ S,
                                const float* __restrict__ Q,
                                const float* __restrict__ Wd, const float* __restrict__ bd,
                                const float* __restrict__ Wc, const float* __restrict__ bc,
                                float* __restrict__ out, int stepIdx) {
    int b = blockIdx.x;
    int m = threadIdx.x;  // 64 threads = 1 wave

    __shared__ float Hs[D_MODEL];
    Hs[m]      = hstate[b * D_MODEL + m];
    Hs[m + 64] = hstate[b * D_MODEL + 64 + m];
    __syncthreads();

    const float* Srow = S + (size_t)(b * NWIN + m) * D_MODEL;
    float acc = 0.f;
#pragma unroll
    for (int jj = 0; jj < D_MODEL; ++jj)
        acc = fmaf(Hs[jj], Srow[jj], acc);

    float mx = acc;
#pragma unroll
    for (int d = 1; d < 64; d <<= 1) mx = fmaxf(mx, __shfl_xor(mx, d));
    float e = __expf(acc - mx);
    float se = e;
#pragma unroll
    for (int d = 1; d < 64; d <<= 1) se += __shfl_xor(se, d);
    float A = e / se;

    float qa = Q[b * NWIN + m] * A;
#pragma unroll
    for (int d = 1; d < 64; d <<= 1) qa += __shfl_xor(qa, d);

    float po = Hs[m] * Wd[m] + Hs[m + 64] * Wd[m + 64];
#pragma unroll
    for (int d = 1; d < 64; d <<= 1) po += __shfl_xor(po, d);

    if (m == 0) {
        float o = po + bd[0];
        float u = sigf(fmaf(qa, Wc[0], bc[0]));
        float y = o + u;
        xext[(size_t)b * XSTRIDE + SEQ_LEN + stepIdx] = y;
        out[b * PRED_LEN + stepIdx] = y;
        out[BATCH * PRED_LEN + b * PRED_LEN + stepIdx] = u;
    }
}

// ---------------------------------------------------------------------------
// kernel_launch
// ---------------------------------------------------------------------------
extern "C" void kernel_launch(void* const* d_in, const int* in_sizes, int n_in,
                              void* d_out, int out_size, void* d_ws, size_t ws_size,
                              hipStream_t stream) {
    const float* batch_x = (const float*)d_in[0];
    const float* Wi_g = (const float*)d_in[4];
    const float* Wh_g = (const float*)d_in[5];
    const float* bi_g = (const float*)d_in[6];
    const float* bh_g = (const float*)d_in[7];
    const float* Wi_w = (const float*)d_in[8];
    const float* Wh_w = (const float*)d_in[9];
    const float* bi_w = (const float*)d_in[10];
    const float* bh_w = (const float*)d_in[11];
    const float* Wd   = (const float*)d_in[12];
    const float* bd   = (const float*)d_in[13];
    const float* Wc   = (const float*)d_in[16];
    const float* bc   = (const float*)d_in[17];
    float* out = (float*)d_out;

    // workspace layout
    float* ws = (float*)d_ws;
    float* xext   = ws;                                   // 131328 f
    float* hstate = xext + BATCH * XSTRIDE;               // 8192 f
    float* Q      = hstate + BATCH * D_MODEL;             // 4096 f
    float* Sbuf   = Q + BATCH * NWIN;                     // 524288 f
    int*   starts = (int*)(Sbuf + (size_t)BATCH * NWIN * D_MODEL); // 4096 i
    _Float16* wh16g = (_Float16*)(starts + BATCH * NWIN); // 49152 h
    _Float16* wh16w = wh16g + 384 * 128;                  // 49152 h

    init_kernel<<<512, 256, 0, stream>>>(batch_x, xext);
    convert_kernel<<<192, 256, 0, stream>>>(Wh_g, Wh_w, wh16g, wh16w);

    for (int i = 0; i < PRED_LEN; ++i) {
        int T = SEQ_LEN + i;
        int L = (i == 0) ? SEQ_LEN : (SEQ_LEN - 1 + i);

        prep_kernel<<<BATCH, 256, 0, stream>>>(xext, starts, Q, T, i);
        gru_fused_kernel<<<MAINB + WINB, NTH, 0, stream>>>(
            xext, hstate, starts, Sbuf,
            wh16g, Wi_g, bi_g, bh_g,
            wh16w, Wi_w, bi_w, bh_w,
            L, (i == 0) ? 1 : 0);
        finalize_kernel<<<BATCH, 64, 0, stream>>>(xext, hstate, Sbuf, Q,
                                                  Wd, bd, Wc, bc, out, i);
    }
}